// Round 4
// baseline (313.189 us; speedup 1.0000x reference)
//
#include <hip/hip_runtime.h>
#include <stdint.h>

// TinyMod fused: x[8192,4096] -> (fcin 32x32) -> 32x blockwise Linear(128->128) -> (fcout 32x32)
// BT=16 rows/WG, 1024 threads (16 waves), grid 512.
// R4: DRAM-granularity fix. x is loaded fully-coalesced (float4, 2KB/wave-instr) and
// transposed through a 16KB LDS chunk buffer (3-deep prefetch pipeline); out goes through
// a 32KB LDS epilogue buffer so each wave stores one contiguous 2KB row-chunk (float4).
// Replaces the old 64B-segment gather/scatter (64+64 dword VMEM/thread -> 16+16 dwordx4).
// Stage-2/3 core (af-hoist, batched b128 W-loads, wch, raw lgkm-only barriers) unchanged.

#define BT    16
#define NTHR  1024
#define GRID  512      // 8192 / BT
#define IDIM  4096
#define ODIM  4096

typedef __attribute__((ext_vector_type(8))) __bf16 bf16x8;
typedef __attribute__((ext_vector_type(4))) float  floatx4;

union BF8 { uint32_t w[4]; unsigned short h[8]; bf16x8 v; };

__device__ __forceinline__ unsigned short f2bf(float f) {
    return __builtin_bit_cast(unsigned short, (__bf16)f);   // RNE, compiler packs pairs
}

// ylds[c:32][bt:16][m:128]: bt-pitch 136 (16B-aligned b128 frags), c-pitch 2184.
// Proven conflict-free-ish in R2/R3 (2.36M total conflicts). 139,776 B.
#define YP_BT 136
#define YP_C  2184
// wch[n':16][bt:16][c:32]: bt-pitch 36, n'-pitch 584; double-buffered, aliased into ylds.
#define WP_BT 36
#define WP_N  584
#define WCH_ELE (16 * WP_N)      // 9344 elems per half
// obuf[bt:16][col:512] f32, pitch 516 (2-way-free writes); aliased into ylds after wch.
#define OB_P  516

// Raw barrier: LDS ordering only (lgkmcnt). NO vmcnt drain -> global loads/stores
// stay in flight across barriers. Compiler fence after s_barrier, no sched pin.
__device__ __forceinline__ void bar_lgkm() {
    asm volatile("s_waitcnt lgkmcnt(0)" ::: "memory");
    __builtin_amdgcn_s_barrier();
    asm volatile("" ::: "memory");
}

template<bool WBF16>
__global__ __launch_bounds__(NTHR, 4)    // VGPR cap 128
void tinymod_fused(const float* __restrict__ x,
                   const float* __restrict__ W_in,
                   const float* __restrict__ b_in,
                   const void*  __restrict__ wmods,
                   const float* __restrict__ b_mods,
                   const float* __restrict__ W_out,
                   const float* __restrict__ b_out,
                   float* __restrict__ out)
{
    __shared__ unsigned short ylds[32 * YP_C] __attribute__((aligned(16))); // 139,776 B
    __shared__ unsigned short xbuf[8192]      __attribute__((aligned(16))); //  16,384 B
    unsigned short* const wch  = ylds;                                  // dead after hoist
    float* const obuf = (float*)((char*)ylds + 4 * WCH_ELE);            // byte 37,376

    const int tid  = threadIdx.x;
    const int lane = tid & 63;
    const int wave = tid >> 6;      // 0..15
    const int l15  = lane & 15;
    const int grp  = lane >> 4;     // 0..3
    const int row0 = blockIdx.x * BT;

    // ---- tiny operand preloads (held in VGPRs whole kernel) ----
    const float bin0 = b_in[l15],  bin1 = b_in[16 + l15];
    const float bo0  = b_out[l15], bo1  = b_out[16 + l15];
    BF8 winf[2], woutf[2];
    #pragma unroll
    for (int cc = 0; cc < 2; cc++) {
        const float* p = W_in  + (l15 + 16*cc) * 32 + grp * 8;  // B[k=i][col=c]
        const float* q = W_out + (l15 + 16*cc) * 32 + grp * 8;  // B[k=c][col=o]
        #pragma unroll
        for (int j = 0; j < 8; j++) { winf[cc].h[j] = f2bf(p[j]); woutf[cc].h[j] = f2bf(q[j]); }
    }

    // ---------------- Stage 1: x -> y (fcin), LDS-transposed chunks ----------------
    // chunk cb = 2 batch rows. Load coalesced (thread: 8 consecutive floats of one row),
    // ds_write_b128 into xbuf[bt2][mt:8][i:32][mi:16] (bf16), fragment-gather from LDS.
    const int bt2 = tid >> 9;            // staging: row within chunk
    const int C0  = (tid & 511) * 8;     // staging: col offset in the row
    const int xw  = ((bt2*8 + ((C0 >> 4) & 7))*32 + (C0 >> 7))*16 + (C0 & 15);
    const int bt2w = wave >> 3;          // compute: row within chunk
    const int mbw  = wave & 7;           // compute: m-subtile
    const int fb   = ((bt2w*8 + mbw)*32 + grp*8)*16 + l15;

    float xr[3][8];                      // 3-deep chunk prefetch pipeline
    #pragma unroll
    for (int p = 0; p < 3; p++) {
        const float* ptr = x + (row0 + 2*p + bt2)*IDIM + C0;
        const float4 f0 = *(const float4*)ptr;
        const float4 f1 = *(const float4*)(ptr + 4);
        xr[p][0]=f0.x; xr[p][1]=f0.y; xr[p][2]=f0.z; xr[p][3]=f0.w;
        xr[p][4]=f1.x; xr[p][5]=f1.y; xr[p][6]=f1.z; xr[p][7]=f1.w;
    }

    #pragma unroll
    for (int cb = 0; cb < 8; cb++) {
        const int s = cb % 3;            // compile-time (loop fully unrolled)
        BF8 t;
        #pragma unroll
        for (int j = 0; j < 8; j++) t.h[j] = f2bf(xr[s][j]);
        uint4 val; val.x = t.w[0]; val.y = t.w[1]; val.z = t.w[2]; val.w = t.w[3];
        *(uint4*)&xbuf[xw] = val;
        if (cb + 3 < 8) {                // refill slot; ~3 chunk-iterations of latency cover
            const float* ptr = x + (row0 + 2*(cb+3) + bt2)*IDIM + C0;
            const float4 f0 = *(const float4*)ptr;
            const float4 f1 = *(const float4*)(ptr + 4);
            xr[s][0]=f0.x; xr[s][1]=f0.y; xr[s][2]=f0.z; xr[s][3]=f0.w;
            xr[s][4]=f1.x; xr[s][5]=f1.y; xr[s][6]=f1.z; xr[s][7]=f1.w;
        }
        bar_lgkm();                      // xbuf chunk ready

        // compute: wave (bt2w, mbw); A[m=l15][k=i=grp*8+j] gathered from LDS
        BF8 a;
        #pragma unroll
        for (int j = 0; j < 8; j++) a.h[j] = xbuf[fb + j*16];
        #pragma unroll
        for (int cc = 0; cc < 2; cc++) {
            floatx4 acc = {0.f, 0.f, 0.f, 0.f};
            acc = __builtin_amdgcn_mfma_f32_16x16x32_bf16(a.v, winf[cc].v, acc, 0, 0, 0);
            const float bi = cc ? bin1 : bin0;
            unsigned short h[4];
            #pragma unroll
            for (int r = 0; r < 4; r++) h[r] = f2bf(acc[r] + bi);   // D row grp*4+r = m
            uint2 pk;
            pk.x = (uint32_t)h[0] | ((uint32_t)h[1] << 16);
            pk.y = (uint32_t)h[2] | ((uint32_t)h[3] << 16);
            *(uint2*)&ylds[(l15 + 16*cc)*YP_C + (2*cb + bt2w)*YP_BT + mbw*16 + grp*4] = pk;
        }
        bar_lgkm();                      // xbuf consumed -> next chunk may overwrite
    }

    // ---- hoist stage-2 A-fragments: wave owns c = 2*wave + {0,1}; A[bt=l15][k=m] ----
    BF8 af[2][4];
    #pragma unroll
    for (int ci = 0; ci < 2; ci++) {
        const int c = 2*wave + ci;
        #pragma unroll
        for (int kc = 0; kc < 4; kc++) {
            const uint4 v = *(const uint4*)&ylds[c*YP_C + l15*YP_BT + kc*32 + grp*8];
            af[ci][kc].w[0] = v.x; af[ci][kc].w[1] = v.y;
            af[ci][kc].w[2] = v.z; af[ci][kc].w[3] = v.w;
        }
    }
    bar_lgkm();     // af reads drained -> ylds space reusable as wch/obuf

    // ---------------- Stage 2+3: y -> w -> out, 8 n-blocks of 16 ----------------
    const unsigned short* __restrict__ wm16 = (const unsigned short*)wmods;
    const float*          __restrict__ wm32 = (const float*)wmods;

    #pragma unroll
    for (int nb = 0; nb < 8; nb++) {
        unsigned short* const wchb = wch + (nb & 1) * WCH_ELE;

        // stage 2: batch all 8 B-fragments before MFMAs (one L2 latency window)
        float bm[2];
        BF8 b[2][4];
        #pragma unroll
        for (int ci = 0; ci < 2; ci++) {
            const int c = 2*wave + ci;
            bm[ci] = b_mods[c*128 + nb*16 + l15];
            #pragma unroll
            for (int kc = 0; kc < 4; kc++) {
                const int wbase = (c*128 + nb*16 + l15)*128 + kc*32 + grp*8;
                if (WBF16) {
                    const uint4 bv = *(const uint4*)&wm16[wbase];
                    b[ci][kc].w[0] = bv.x; b[ci][kc].w[1] = bv.y;
                    b[ci][kc].w[2] = bv.z; b[ci][kc].w[3] = bv.w;
                } else {
                    const float* wp = wm32 + wbase;
                    #pragma unroll
                    for (int j = 0; j < 8; j++) b[ci][kc].h[j] = f2bf(wp[j]);
                }
            }
        }
        floatx4 acc[2];
        #pragma unroll
        for (int ci = 0; ci < 2; ci++) {
            floatx4 s = {0.f, 0.f, 0.f, 0.f};
            #pragma unroll
            for (int kc = 0; kc < 4; kc++)
                s = __builtin_amdgcn_mfma_f32_16x16x32_bf16(af[ci][kc].v, b[ci][kc].v, s, 0, 0, 0);
            acc[ci] = s;
        }
        #pragma unroll
        for (int r = 0; r < 4; r++) {
            const unsigned short h0 = f2bf(acc[0][r] + bm[0]);
            const unsigned short h1 = f2bf(acc[1][r] + bm[1]);
            const uint32_t pk = (uint32_t)h0 | ((uint32_t)h1 << 16);
            *(uint32_t*)&wchb[l15*WP_N + (grp*4 + r)*WP_BT + 2*wave] = pk;
        }
        bar_lgkm();     // wch ready (also: all epilogue obuf-reads of nb-1 drained)

        // stage 3: wave owns n' = wave; A[bt=l15][k=c:32]
        BF8 a3;
        {
            const int off = wave*WP_N + l15*WP_BT + grp*8;
            const uint2 u0 = *(const uint2*)&wchb[off];
            const uint2 u1 = *(const uint2*)&wchb[off + 4];
            a3.w[0] = u0.x; a3.w[1] = u0.y; a3.w[2] = u1.x; a3.w[3] = u1.y;
        }
        #pragma unroll
        for (int oc = 0; oc < 2; oc++) {
            floatx4 v = {0.f, 0.f, 0.f, 0.f};
            v = __builtin_amdgcn_mfma_f32_16x16x32_bf16(a3.v, woutf[oc].v, v, 0, 0, 0);
            const float bo = oc ? bo1 : bo0;
            #pragma unroll
            for (int r = 0; r < 4; r++)      // D row = bt = grp*4+r
                obuf[(grp*4 + r)*OB_P + wave*32 + oc*16 + l15] = v[r] + bo;
        }
        bar_lgkm();     // obuf ready

        // epilogue: wave stores one contiguous 2KB row-chunk (float4 x2)
        {
            const int ec = (tid & 63) * 8;
            const float4 o0 = *(const float4*)&obuf[wave*OB_P + ec];
            const float4 o1 = *(const float4*)&obuf[wave*OB_P + ec + 4];
            float* po = out + (row0 + wave)*ODIM + nb*512 + ec;
            *(float4*)po       = o0;
            *(float4*)(po + 4) = o1;     // stores drain in background (no vmcnt(0))
        }
    }
}

// prologue: W_mods fp32 -> bf16 into workspace (2 MiB -> 1 MiB, L2/L3 resident)
__global__ void wmods_to_bf16(const float* __restrict__ w, unsigned short* __restrict__ o) {
    const int i = (blockIdx.x * 256 + threadIdx.x) * 4;
    const float4 f = *(const float4*)(w + i);
    uint2 pk;
    pk.x = (uint32_t)f2bf(f.x) | ((uint32_t)f2bf(f.y) << 16);
    pk.y = (uint32_t)f2bf(f.z) | ((uint32_t)f2bf(f.w) << 16);
    *(uint2*)(o + i) = pk;
}

extern "C" void kernel_launch(void* const* d_in, const int* in_sizes, int n_in,
                              void* d_out, int out_size, void* d_ws, size_t ws_size,
                              hipStream_t stream)
{
    const float* x     = (const float*)d_in[0];
    const float* W_in  = (const float*)d_in[1];
    const float* b_in  = (const float*)d_in[2];
    const float* Wm    = (const float*)d_in[3];
    const float* b_m   = (const float*)d_in[4];
    const float* W_out = (const float*)d_in[5];
    const float* b_out = (const float*)d_in[6];
    float* out = (float*)d_out;

    const size_t wm_elems = 32u * 128u * 128u;   // 524288
    if (ws_size >= wm_elems * sizeof(unsigned short)) {
        unsigned short* wbf = (unsigned short*)d_ws;
        wmods_to_bf16<<<(int)(wm_elems / (256 * 4)), 256, 0, stream>>>(Wm, wbf);
        tinymod_fused<true><<<GRID, NTHR, 0, stream>>>(x, W_in, b_in, (const void*)wbf,
                                                       b_m, W_out, b_out, out);
    } else {
        tinymod_fused<false><<<GRID, NTHR, 0, stream>>>(x, W_in, b_in, (const void*)Wm,
                                                        b_m, W_out, b_out, out);
    }
}